// Round 4
// baseline (612.648 us; speedup 1.0000x reference)
//
#include <hip/hip_runtime.h>
#include <hip/hip_bf16.h>
#include <math.h>

#define B_IMG 16
#define HH 112
#define WW_ 112
#define CC 128
#define LL (HH*WW_)            // 12544
#define BWIN 4096
#define NTOK 49
#define NROWS (BWIN*NTOK)      // 200704
#define HD 32
#define SCALE 0.1767766952966369f   // 1/sqrt(32)
#define SHIFT_ 3

typedef short bf16x8 __attribute__((ext_vector_type(8)));
typedef float f32x4 __attribute__((ext_vector_type(4)));
typedef unsigned short ushort_t;

// ---------------------------------------------------------------- helpers
__device__ __forceinline__ float wave_sum(float v) {
#pragma unroll
  for (int off = 32; off >= 1; off >>= 1) v += __shfl_xor(v, off, 64);
  return v;
}

// fast GELU (tanh form, hw exp). |err vs erf-GELU| <~1.5e-3; bf16-negligible.
__device__ __forceinline__ float gelu_f(float x) {
  float x3 = x * x * x;
  float y = 0.7978845608028654f * fmaf(0.044715f, x3, x);
  float e = __expf(2.f * y);               // v_exp_f32 path
  float th = 1.f - 2.f / (e + 1.f);        // tanh(y), saturates correctly
  return 0.5f * x * (1.f + th);
}

__global__ __launch_bounds__(256) void castw_kernel(const float* __restrict__ w,
                                                    __hip_bfloat16* __restrict__ o, int n) {
  int i = blockIdx.x * 256 + threadIdx.x;
  if (i < n) o[i] = __float2bfloat16(w[i]);
}

// ---------------------------------------------------------------- attention prep tables
__global__ __launch_bounds__(256) void prep_bias(const float* __restrict__ table,
                                                 float* __restrict__ biasPad) {
  int idx = blockIdx.x * 256 + threadIdx.x;      // 4*64*64 = 16384
  int h = idx >> 12, q = (idx >> 6) & 63, k = idx & 63;
  float v = 0.f;
  if (q < NTOK && k < NTOK) {
    int yi = q / 7, xi = q % 7, yj = k / 7, xj = k % 7;
    v = table[((yi - yj + 6) * 13 + (xi - xj + 6)) * 4 + h];
  }
  biasPad[idx] = v;
}

__global__ __launch_bounds__(256) void prep_mask(const float* __restrict__ mask,
                                                 float* __restrict__ maskPad) {
  int idx = blockIdx.x * 256 + threadIdx.x;      // 256*64*64 = 1048576
  int pat = idx >> 12, q = (idx >> 6) & 63, k = idx & 63;
  float v = -1e30f;
  if (q < NTOK && k < NTOK) v = mask[pat * (NTOK * NTOK) + q * NTOK + k];
  maskPad[idx] = v;
}

// ---------------------------------------------------------------- LayerNorm (fp32 in, bf16 out)
template<bool GATHER>
__global__ __launch_bounds__(256) void ln_kernel(
    const float* __restrict__ X, const float* __restrict__ g,
    const float* __restrict__ b, __hip_bfloat16* __restrict__ Y)
{
  int wid  = threadIdx.x >> 6;
  int lane = threadIdx.x & 63;
  int r = blockIdx.x * 4 + wid;
  size_t src;
  if (GATHER) {
    int win = r / NTOK, n = r % NTOK;
    int bi = win >> 8, wi = win & 255;
    int wh = wi >> 4, wwi = wi & 15;
    int ii = n / 7, jj = n % 7;
    int hp = wh * 7 + ii, wp = wwi * 7 + jj;
    int sh = (hp + SHIFT_) % HH, sw = (wp + SHIFT_) % WW_;   // roll(-3) gather
    src = ((size_t)bi * LL + (size_t)sh * WW_ + sw) * CC;
  } else {
    src = (size_t)r * CC;
  }
  float v0 = X[src + lane];
  float v1 = X[src + 64 + lane];
  float mean = wave_sum(v0 + v1) * (1.f / CC);
  float d0 = v0 - mean, d1 = v1 - mean;
  float var = wave_sum(d0 * d0 + d1 * d1) * (1.f / CC);
  float rstd = rsqrtf(var + 1e-5f);
  size_t dst = (size_t)r * CC;
  Y[dst + lane]      = __float2bfloat16(d0 * rstd * g[lane]      + b[lane]);
  Y[dst + 64 + lane] = __float2bfloat16(d1 * rstd * g[lane + 64] + b[lane + 64]);
}

// ---------------------------------------------------------------- bf16 MFMA GEMM
enum { EPI_BIAS = 0, EPI_GELU = 1, EPI_RES = 2, EPI_PROJ = 3 };
#define LDSW 136   // 128 + 8 pad: keeps 16B alignment, breaks bank-phase

#define STAGE_A(KB)                                                              \
  _Pragma("unroll")                                                              \
  for (int p = 0; p < 8; ++p) {                                                  \
    int lin = p * 256 + t;                                                       \
    int row = lin >> 4;                                                          \
    int col = (lin & 15) * 8;                                                    \
    *(uint4*)&As[row * LDSW + col] =                                             \
        *(const uint4*)(A + (size_t)(m0 + row) * K + (KB) + col);                \
  }

#define STAGE_B(NOFF, KB)                                                        \
  _Pragma("unroll")                                                              \
  for (int p = 0; p < 8; ++p) {                                                  \
    int lin = p * 256 + t;                                                       \
    int row = lin >> 4;                                                          \
    int col = (lin & 15) * 8;                                                    \
    *(uint4*)&Bs[row * LDSW + col] =                                             \
        *(const uint4*)(W + (size_t)((NOFF) + row) * K + (KB) + col);            \
  }

#define MFMA_BLOCK                                                               \
  _Pragma("unroll")                                                              \
  for (int ks = 0; ks < 4; ++ks) {                                               \
    int k0 = ks * 32 + quad * 8;                                                 \
    bf16x8 af[4], bf[4];                                                         \
    _Pragma("unroll")                                                            \
    for (int i = 0; i < 4; ++i)                                                  \
      af[i] = *(const bf16x8*)&As[(wr + i * 16 + l16) * LDSW + k0];              \
    _Pragma("unroll")                                                            \
    for (int j = 0; j < 4; ++j)                                                  \
      bf[j] = *(const bf16x8*)&Bs[(wc + j * 16 + l16) * LDSW + k0];              \
    _Pragma("unroll")                                                            \
    for (int i = 0; i < 4; ++i)                                                  \
      _Pragma("unroll")                                                          \
      for (int j = 0; j < 4; ++j)                                                \
        acc[i][j] = __builtin_amdgcn_mfma_f32_16x16x32_bf16(af[i], bf[j],        \
                                                            acc[i][j], 0, 0, 0); \
  }

template<int EPI, int NB, bool LNF>
__global__ __launch_bounds__(256, 2) void gemm_bf16(
    const ushort_t* __restrict__ A, const ushort_t* __restrict__ W,
    const float* __restrict__ bias, const float* __restrict__ aux,
    void* __restrict__ outp, const float* __restrict__ g2,
    const float* __restrict__ b2, __hip_bfloat16* __restrict__ ln_out,
    int N, int K)
{
  __shared__ ushort_t As[128 * LDSW];
  __shared__ ushort_t Bs[128 * LDSW];
  int t = threadIdx.x;
  int lane = t & 63;
  int quad = lane >> 4;
  int l16  = lane & 15;
  int wr = (t >> 7) * 64;        // wave row offset in tile
  int wc = ((t >> 6) & 1) * 64;  // wave col offset in tile
  int m0 = blockIdx.x * 128;

  f32x4 acc[4][4];

  for (int nb = 0; nb < NB; ++nb) {
    int n_off = (NB == 1) ? blockIdx.y * 128 : nb * 128;
#pragma unroll
    for (int i = 0; i < 4; ++i)
#pragma unroll
      for (int j = 0; j < 4; ++j) acc[i][j] = (f32x4){0.f, 0.f, 0.f, 0.f};

    if (NB == 1) {
      for (int kb = 0; kb < K; kb += 128) {
        if (kb) __syncthreads();
        STAGE_A(kb);
        STAGE_B(n_off, kb);
        __syncthreads();
        MFMA_BLOCK;
      }
    } else {           // K == 128: A resident across B panels
      if (nb == 0) { STAGE_A(0); STAGE_B(0, 0); }
      __syncthreads();
      MFMA_BLOCK;
      __syncthreads();
      if (nb + 1 < NB) { STAGE_B((nb + 1) * 128, 0); }
    }

    // ---------------- epilogue: C/D layout col=lane&15, row=quad*4+reg
    if (EPI == EPI_PROJ) {
      float s[4][4], ss[4][4];
      unsigned rowB[4][4];
#pragma unroll
      for (int i = 0; i < 4; ++i) {
#pragma unroll
        for (int r = 0; r < 4; ++r) {
          s[i][r] = 0.f; ss[i][r] = 0.f;
          int m = m0 + wr + i * 16 + quad * 4 + r;
          int win = m / NTOK, nn = m % NTOK;
          int bi = win >> 8, wi = win & 255;
          int wh = wi >> 4, wwi = wi & 15;
          int ii = nn / 7, jj = nn % 7;
          int hp = wh * 7 + ii, wp = wwi * 7 + jj;
          int oh = (hp + SHIFT_) % HH, ow = (wp + SHIFT_) % WW_;
          unsigned base = ((unsigned)bi * LL + (unsigned)oh * WW_ + ow) * CC;
          rowB[i][r] = base;
#pragma unroll
          for (int j = 0; j < 4; ++j) {
            int n = wc + j * 16 + l16;
            float x1 = aux[base + n] + acc[i][j][r] + bias[n];
            ((float*)outp)[base + n] = x1;
            if (LNF) {
              acc[i][j][r] = x1;
              s[i][r] += x1;
              ss[i][r] = fmaf(x1, x1, ss[i][r]);
            }
          }
        }
      }
      if (LNF) {
#pragma unroll
        for (int i = 0; i < 4; ++i)
#pragma unroll
          for (int r = 0; r < 4; ++r) {
#pragma unroll
            for (int off = 8; off >= 1; off >>= 1) {
              s[i][r]  += __shfl_xor(s[i][r],  off, 64);
              ss[i][r] += __shfl_xor(ss[i][r], off, 64);
            }
          }
        float* red = (float*)As;              // [2][128][2] = 2 KB
        __syncthreads();                      // all waves done reading As
        if (l16 == 0) {
#pragma unroll
          for (int i = 0; i < 4; ++i)
#pragma unroll
            for (int r = 0; r < 4; ++r) {
              int ml = wr + i * 16 + quad * 4 + r;
              red[((wc >> 6) * 128 + ml) * 2 + 0] = s[i][r];
              red[((wc >> 6) * 128 + ml) * 2 + 1] = ss[i][r];
            }
        }
        __syncthreads();
#pragma unroll
        for (int i = 0; i < 4; ++i)
#pragma unroll
          for (int r = 0; r < 4; ++r) {
            int ml = wr + i * 16 + quad * 4 + r;
            float st  = red[ml * 2 + 0] + red[(128 + ml) * 2 + 0];
            float sst = red[ml * 2 + 1] + red[(128 + ml) * 2 + 1];
            float mean = st * (1.f / 128.f);
            float var  = sst * (1.f / 128.f) - mean * mean;
            s[i][r]  = mean;
            ss[i][r] = rsqrtf(var + 1e-5f);
          }
#pragma unroll
        for (int i = 0; i < 4; ++i)
#pragma unroll
          for (int r = 0; r < 4; ++r) {
            unsigned base = rowB[i][r];
#pragma unroll
            for (int j = 0; j < 4; ++j) {
              int n = wc + j * 16 + l16;
              float ln = (acc[i][j][r] - s[i][r]) * ss[i][r] * g2[n] + b2[n];
              ln_out[(size_t)base + n] = __float2bfloat16(ln);
            }
          }
      }
    } else {
#pragma unroll
      for (int i = 0; i < 4; ++i) {
#pragma unroll
        for (int j = 0; j < 4; ++j) {
          int n = n_off + wc + j * 16 + l16;
          float bn = bias[n];
#pragma unroll
          for (int reg = 0; reg < 4; ++reg) {
            int m = m0 + wr + i * 16 + quad * 4 + reg;
            float v = acc[i][j][reg] + bn;
            if (EPI == EPI_BIAS) {
              ((__hip_bfloat16*)outp)[(size_t)m * N + n] = __float2bfloat16(v);
            } else if (EPI == EPI_GELU) {
              v = gelu_f(v);
              ((__hip_bfloat16*)outp)[(size_t)m * N + n] = __float2bfloat16(v);
            } else { // EPI_RES: in-place residual (aux aliases outp)
              ((float*)outp)[(size_t)m * N + n] = v + aux[(size_t)m * N + n];
            }
          }
        }
      }
    }
  }
}

// ---------------------------------------------------------------- fused MLP
// out[m][0:128] += fc2(gelu(fc1(A[m]))) ; h1 lives only in LDS.
// Block = 64 rows. Waves 2x2: wr in {0,32}, wc in {0,64}.
// Per hid-chunk nb (128 wide): stage W1_nb -> Bs, fc1 MFMA, GELU -> Hs,
// restage Bs with W2_nb, fc2 MFMA-accumulate.
__global__ __launch_bounds__(256, 2) void mlp_fused(
    const ushort_t* __restrict__ A,      // [NROWS][128] bf16 (LN2 out, linear)
    const ushort_t* __restrict__ W1,     // [512][128] bf16
    const float* __restrict__ b1,        // [512]
    const ushort_t* __restrict__ W2,     // [128][512] bf16
    const float* __restrict__ b2,        // [128]
    float* __restrict__ out)             // [NROWS][128] fp32, in-place residual
{
  __shared__ ushort_t As[64 * LDSW];
  __shared__ ushort_t Bs[128 * LDSW];
  __shared__ ushort_t Hs[64 * LDSW];
  int t = threadIdx.x;
  int lane = t & 63;
  int quad = lane >> 4;
  int l16  = lane & 15;
  int wr = (t >> 7) * 32;        // 0 / 32
  int wc = ((t >> 6) & 1) * 64;  // 0 / 64
  int m0 = blockIdx.x * 64;

  // stage A: 64 x 128
#pragma unroll
  for (int p = 0; p < 4; ++p) {
    int lin = p * 256 + t;
    int row = lin >> 4, col = (lin & 15) * 8;
    *(uint4*)&As[row * LDSW + col] = *(const uint4*)(A + (size_t)(m0 + row) * 128 + col);
  }

  f32x4 acc2[2][4];
#pragma unroll
  for (int i = 0; i < 2; ++i)
#pragma unroll
    for (int j = 0; j < 4; ++j) acc2[i][j] = (f32x4){0.f, 0.f, 0.f, 0.f};

  for (int nb = 0; nb < 4; ++nb) {
    __syncthreads();   // prev fc2 reads of Bs/Hs done; As visible (nb==0)
    // stage W1 panel nb (128 x 128)
#pragma unroll
    for (int p = 0; p < 8; ++p) {
      int lin = p * 256 + t;
      int row = lin >> 4, col = (lin & 15) * 8;
      *(uint4*)&Bs[row * LDSW + col] =
          *(const uint4*)(W1 + (size_t)(nb * 128 + row) * 128 + col);
    }
    __syncthreads();
    // fc1: h1 chunk = A x W1_nb^T
    f32x4 acc1[2][4];
#pragma unroll
    for (int i = 0; i < 2; ++i)
#pragma unroll
      for (int j = 0; j < 4; ++j) acc1[i][j] = (f32x4){0.f, 0.f, 0.f, 0.f};
#pragma unroll
    for (int ks = 0; ks < 4; ++ks) {
      int k0 = ks * 32 + quad * 8;
      bf16x8 af[2], bf[4];
#pragma unroll
      for (int i = 0; i < 2; ++i)
        af[i] = *(const bf16x8*)&As[(wr + i * 16 + l16) * LDSW + k0];
#pragma unroll
      for (int j = 0; j < 4; ++j)
        bf[j] = *(const bf16x8*)&Bs[(wc + j * 16 + l16) * LDSW + k0];
#pragma unroll
      for (int i = 0; i < 2; ++i)
#pragma unroll
        for (int j = 0; j < 4; ++j)
          acc1[i][j] = __builtin_amdgcn_mfma_f32_16x16x32_bf16(af[i], bf[j], acc1[i][j], 0, 0, 0);
    }
    __syncthreads();   // all fc1 reads of Bs done -> safe to overwrite with W2
    // GELU + bias -> Hs (bf16)
#pragma unroll
    for (int i = 0; i < 2; ++i)
#pragma unroll
      for (int j = 0; j < 4; ++j) {
        int hc = wc + j * 16 + l16;
        float bn = b1[nb * 128 + hc];
#pragma unroll
        for (int r = 0; r < 4; ++r) {
          int hr = wr + i * 16 + quad * 4 + r;
          float v = gelu_f(acc1[i][j][r] + bn);
          *(__hip_bfloat16*)&Hs[hr * LDSW + hc] = __float2bfloat16(v);
        }
      }
    // stage W2 panel nb (128 out-ch x 128 k) into Bs
#pragma unroll
    for (int p = 0; p < 8; ++p) {
      int lin = p * 256 + t;
      int row = lin >> 4, col = (lin & 15) * 8;
      *(uint4*)&Bs[row * LDSW + col] =
          *(const uint4*)(W2 + (size_t)row * 512 + nb * 128 + col);
    }
    __syncthreads();
    // fc2: acc2 += Hs x W2_nb^T
#pragma unroll
    for (int ks = 0; ks < 4; ++ks) {
      int k0 = ks * 32 + quad * 8;
      bf16x8 hf[2], wf[4];
#pragma unroll
      for (int i = 0; i < 2; ++i)
        hf[i] = *(const bf16x8*)&Hs[(wr + i * 16 + l16) * LDSW + k0];
#pragma unroll
      for (int j = 0; j < 4; ++j)
        wf[j] = *(const bf16x8*)&Bs[(wc + j * 16 + l16) * LDSW + k0];
#pragma unroll
      for (int i = 0; i < 2; ++i)
#pragma unroll
        for (int j = 0; j < 4; ++j)
          acc2[i][j] = __builtin_amdgcn_mfma_f32_16x16x32_bf16(hf[i], wf[j], acc2[i][j], 0, 0, 0);
    }
  }

  // epilogue: out += acc2 + b2
#pragma unroll
  for (int i = 0; i < 2; ++i)
#pragma unroll
    for (int j = 0; j < 4; ++j) {
      int n = wc + j * 16 + l16;
      float bn = b2[n];
#pragma unroll
      for (int r = 0; r < 4; ++r) {
        int m = m0 + wr + i * 16 + quad * 4 + r;
        out[(size_t)m * 128 + n] += acc2[i][j][r] + bn;
      }
    }
}

// ---------------------------------------------------------------- MFMA attention
#define WLDS 6656

__global__ __launch_bounds__(256) void attn_mfma(
    const ushort_t* __restrict__ qkv, const float* __restrict__ maskPad,
    const float* __restrict__ biasPad, __hip_bfloat16* __restrict__ O, int win_off)
{
  __shared__ ushort_t lds[4 * WLDS];
  const int win_l = blockIdx.x;
  const int win_g = win_off + win_l;
  const int h    = threadIdx.x >> 6;
  const int lane = threadIdx.x & 63;
  const int quad = lane >> 4;
  const int l16  = lane & 15;
  ushort_t* wb = lds + h * WLDS;     // Ks, later P
  ushort_t* Vt = wb + 4608;

  {
    const int tok = lane;
    uint4 z = make_uint4(0u, 0u, 0u, 0u);
    uint4 k0 = z, k1 = z, k2 = z, k3 = z;
    union { uint4 v4[4]; ushort_t u[32]; } vv;
    vv.v4[0] = z; vv.v4[1] = z; vv.v4[2] = z; vv.v4[3] = z;
    if (tok < NTOK) {
      const ushort_t* src = qkv + ((size_t)win_l * NTOK + tok) * 384 + h * HD;
      k0 = *(const uint4*)(src + 128); k1 = *(const uint4*)(src + 136);
      k2 = *(const uint4*)(src + 144); k3 = *(const uint4*)(src + 152);
      vv.v4[0] = *(const uint4*)(src + 256); vv.v4[1] = *(const uint4*)(src + 264);
      vv.v4[2] = *(const uint4*)(src + 272); vv.v4[3] = *(const uint4*)(src + 280);
    }
    *(uint4*)&wb[tok * 40 +  0] = k0;
    *(uint4*)&wb[tok * 40 +  8] = k1;
    *(uint4*)&wb[tok * 40 + 16] = k2;
    *(uint4*)&wb[tok * 40 + 24] = k3;
#pragma unroll
    for (int d = 0; d < 32; ++d) Vt[d * 64 + tok] = vv.u[d];
  }

  bf16x8 qf[4];
  {
    const ushort_t* qb = qkv + (size_t)win_l * NTOK * 384 + h * HD + quad * 8;
#pragma unroll
    for (int i = 0; i < 4; ++i)
      qf[i] = *(const bf16x8*)(qb + (size_t)(i * 16 + l16) * 384);
  }

  f32x4 S[4][4];
#pragma unroll
  for (int i = 0; i < 4; ++i)
#pragma unroll
    for (int j = 0; j < 4; ++j) S[i][j] = (f32x4){0.f, 0.f, 0.f, 0.f};
  bf16x8 kf[4];
#pragma unroll
  for (int j = 0; j < 4; ++j)
    kf[j] = *(const bf16x8*)&wb[(j * 16 + l16) * 40 + quad * 8];
#pragma unroll
  for (int i = 0; i < 4; ++i)
#pragma unroll
    for (int j = 0; j < 4; ++j)
      S[i][j] = __builtin_amdgcn_mfma_f32_16x16x32_bf16(qf[i], kf[j], S[i][j], 0, 0, 0);

  const float* mrow = maskPad + (size_t)(win_g & 255) * 4096;
  const float* brow = biasPad + (size_t)h * 4096;
#pragma unroll
  for (int i = 0; i < 4; ++i)
#pragma unroll
    for (int j = 0; j < 4; ++j)
#pragma unroll
      for (int r = 0; r < 4; ++r) {
        int q = i * 16 + quad * 4 + r;
        int k = j * 16 + l16;
        S[i][j][r] = fmaf(S[i][j][r], SCALE, brow[q * 64 + k] + mrow[q * 64 + k]);
      }

  float inv[4][4];
#pragma unroll
  for (int i = 0; i < 4; ++i)
#pragma unroll
    for (int r = 0; r < 4; ++r) {
      float mx = fmaxf(fmaxf(S[i][0][r], S[i][1][r]), fmaxf(S[i][2][r], S[i][3][r]));
      mx = fmaxf(mx, __shfl_xor(mx, 1, 64));
      mx = fmaxf(mx, __shfl_xor(mx, 2, 64));
      mx = fmaxf(mx, __shfl_xor(mx, 4, 64));
      mx = fmaxf(mx, __shfl_xor(mx, 8, 64));
      float sum = 0.f;
#pragma unroll
      for (int j = 0; j < 4; ++j) {
        float e = __expf(S[i][j][r] - mx);
        S[i][j][r] = e;
        sum += e;
      }
      sum += __shfl_xor(sum, 1, 64);
      sum += __shfl_xor(sum, 2, 64);
      sum += __shfl_xor(sum, 4, 64);
      sum += __shfl_xor(sum, 8, 64);
      inv[i][r] = 1.f / sum;
    }

#pragma unroll
  for (int i = 0; i < 4; ++i)
#pragma unroll
    for (int j = 0; j < 4; ++j)
#pragma unroll
      for (int r = 0; r < 4; ++r) {
        int q = i * 16 + quad * 4 + r;
        int k = j * 16 + l16;
        *(__hip_bfloat16*)&wb[q * 72 + k] = __float2bfloat16(S[i][j][r]);
      }

  f32x4 Oacc[4][2];
#pragma unroll
  for (int i = 0; i < 4; ++i) {
    Oacc[i][0] = (f32x4){0.f, 0.f, 0.f, 0.f};
    Oacc[i][1] = (f32x4){0.f, 0.f, 0.f, 0.f};
  }
  bf16x8 vf[2][2];
#pragma unroll
  for (int ks = 0; ks < 2; ++ks)
#pragma unroll
    for (int jp = 0; jp < 2; ++jp)
      vf[ks][jp] = *(const bf16x8*)&Vt[(jp * 16 + l16) * 64 + ks * 32 + quad * 8];
#pragma unroll
  for (int i = 0; i < 4; ++i)
#pragma unroll
    for (int ks = 0; ks < 2; ++ks) {
      bf16x8 pf = *(const bf16x8*)&wb[(i * 16 + l16) * 72 + ks * 32 + quad * 8];
#pragma unroll
      for (int jp = 0; jp < 2; ++jp)
        Oacc[i][jp] = __builtin_amdgcn_mfma_f32_16x16x32_bf16(pf, vf[ks][jp], Oacc[i][jp], 0, 0, 0);
    }

  __hip_bfloat16* ob = O + ((size_t)win_g * NTOK) * CC + h * HD;
#pragma unroll
  for (int i = 0; i < 4; ++i)
#pragma unroll
    for (int r = 0; r < 4; ++r) {
      int q = i * 16 + quad * 4 + r;
      if (q < NTOK) {
        float sc = inv[i][r];
#pragma unroll
        for (int jp = 0; jp < 2; ++jp)
          ob[(size_t)q * CC + jp * 16 + l16] = __float2bfloat16(Oacc[i][jp][r] * sc);
      }
    }
}

// ---------------------------------------------------------------- launch
extern "C" void kernel_launch(void* const* d_in, const int* in_sizes, int n_in,
                              void* d_out, int out_size, void* d_ws, size_t ws_size,
                              hipStream_t stream) {
  const float* x        = (const float*)d_in[0];
  const float* attnmask = (const float*)d_in[3];
  const float* ln1_g    = (const float*)d_in[4];
  const float* ln1_b    = (const float*)d_in[5];
  const float* qkv_w    = (const float*)d_in[6];
  const float* qkv_b    = (const float*)d_in[7];
  const float* table    = (const float*)d_in[8];
  const float* proj_w   = (const float*)d_in[9];
  const float* proj_b   = (const float*)d_in[10];
  const float* ln2_g    = (const float*)d_in[11];
  const float* ln2_b    = (const float*)d_in[12];
  const float* fc1_w    = (const float*)d_in[13];
  const float* fc1_b    = (const float*)d_in[14];
  const float* fc2_w    = (const float*)d_in[15];
  const float* fc2_b    = (const float*)d_in[16];
  float* out = (float*)d_out;   // x1 lives here

  const size_t bufA_elems = (size_t)NROWS * CC;            // 25.7M
  const size_t bufB_full  = (size_t)NROWS * 384;           // 77.1M (qkv)
  const size_t bufB_chunk = (size_t)(NROWS / 2) * 384;     // 38.5M
  const size_t bufC_elems = (size_t)NROWS * CC;            // 25.7M (LN2 out)
  const size_t w_elems    = 384*128 + 128*128 + 512*128 + 128*512;
  const size_t tbl_floats = 4 * 4096 + 256 * 4096;
  const size_t need_full  =
      (bufA_elems + bufB_full + bufC_elems + w_elems) * 2 + tbl_floats * 4;
  const bool full = ws_size >= need_full;

  __hip_bfloat16* bufA = (__hip_bfloat16*)d_ws;            // xw -> o
  __hip_bfloat16* bufB = bufA + bufA_elems;                // qkv (/ h1 in fallback)
  __hip_bfloat16* bufC;                                    // LN2 out (full path)
  __hip_bfloat16* wq;
  if (full) {
    bufC = bufB + bufB_full;
    wq   = bufC + bufC_elems;
  } else {
    bufC = nullptr;
    wq   = bufB + bufB_chunk;
  }
  __hip_bfloat16* wp   = wq + 384 * 128;
  __hip_bfloat16* w1   = wp + 128 * 128;
  __hip_bfloat16* w2   = w1 + 512 * 128;
  float* biasPad = (float*)(w2 + 128 * 512);               // [4][64][64]
  float* maskPad = biasPad + 4 * 4096;                     // [256][64][64]

  // 0. cast weights to bf16 + build padded attn tables
  castw_kernel<<<(384 * 128 + 255) / 256, 256, 0, stream>>>(qkv_w, wq, 384 * 128);
  castw_kernel<<<(128 * 128 + 255) / 256, 256, 0, stream>>>(proj_w, wp, 128 * 128);
  castw_kernel<<<(512 * 128 + 255) / 256, 256, 0, stream>>>(fc1_w, w1, 512 * 128);
  castw_kernel<<<(128 * 512 + 255) / 256, 256, 0, stream>>>(fc2_w, w2, 128 * 512);
  prep_bias<<<64, 256, 0, stream>>>(table, biasPad);
  prep_mask<<<4096, 256, 0, stream>>>(attnmask, maskPad);

  // 1. LN1 + roll + window partition: x -> bufA (bf16)
  ln_kernel<true><<<NROWS / 4, 256, 0, stream>>>(x, ln1_g, ln1_b, bufA);

  if (full) {
    // 2. qkv GEMM (A resident over 3 B-panels): bufA -> bufB
    dim3 g(NROWS / 128, 1);
    gemm_bf16<EPI_BIAS, 3, false><<<g, 256, 0, stream>>>(
        (const ushort_t*)bufA, (const ushort_t*)wq, qkv_b, nullptr, bufB,
        nullptr, nullptr, nullptr, 384, 128);
    // 3. attention: bufB -> bufA (o)
    attn_mfma<<<BWIN, 256, 0, stream>>>((const ushort_t*)bufB, maskPad, biasPad,
                                        bufA, 0);
    // 4. proj GEMM + residual scatter -> out (x1) + fused LN2 -> bufC (linear)
    gemm_bf16<EPI_PROJ, 1, true><<<g, 256, 0, stream>>>(
        (const ushort_t*)bufA, (const ushort_t*)wp, proj_b, x, out,
        ln2_g, ln2_b, bufC, 128, 128);
    // 5. fused MLP: bufC -> out (in-place residual); h1 never leaves LDS
    mlp_fused<<<NROWS / 64, 256, 0, stream>>>(
        (const ushort_t*)bufC, (const ushort_t*)w1, fc1_b,
        (const ushort_t*)w2, fc2_b, out);
  } else {
    // fallback: chunked structure, separate LN2, unfused MLP
    for (int c = 0; c < 2; ++c) {
      const int MC = NROWS / 2;
      const ushort_t* Ain = (const ushort_t*)(bufA + (size_t)c * MC * CC);
      dim3 g(MC / 128, 1);
      gemm_bf16<EPI_BIAS, 3, false><<<g, 256, 0, stream>>>(
          Ain, (const ushort_t*)wq, qkv_b, nullptr, bufB,
          nullptr, nullptr, nullptr, 384, 128);
      attn_mfma<<<2048, 256, 0, stream>>>((const ushort_t*)bufB, maskPad, biasPad,
                                          bufA, c * 2048);
    }
    {
      dim3 g(NROWS / 128, 1);
      gemm_bf16<EPI_PROJ, 1, false><<<g, 256, 0, stream>>>(
          (const ushort_t*)bufA, (const ushort_t*)wp, proj_b, x, out,
          nullptr, nullptr, nullptr, 128, 128);
    }
    ln_kernel<false><<<NROWS / 4, 256, 0, stream>>>(out, ln2_g, ln2_b, bufA);
    for (int c = 0; c < 4; ++c) {
      const int MC = NROWS / 4;
      const ushort_t* Ain = (const ushort_t*)(bufA + (size_t)c * MC * CC);
      float* Oc = out + (size_t)c * MC * CC;
      dim3 g1(MC / 128, 1);
      gemm_bf16<EPI_GELU, 4, false><<<g1, 256, 0, stream>>>(
          Ain, (const ushort_t*)w1, fc1_b, nullptr, bufB,
          nullptr, nullptr, nullptr, 512, 128);
      dim3 g2(MC / 128, 1);
      gemm_bf16<EPI_RES, 1, false><<<g2, 256, 0, stream>>>(
          (const ushort_t*)bufB, (const ushort_t*)w2, fc2_b, Oc, Oc,
          nullptr, nullptr, nullptr, 128, 512);
    }
  }
}